// Round 2
// baseline (580.029 us; speedup 1.0000x reference)
//
#include <hip/hip_runtime.h>
#include <hip/hip_bf16.h>
#include <string.h>

// Problem constants
#define BB 8
#define SS 2048
#define HH 8
#define DKK 64
#define HD 512   // H*DK
#define DM 512

typedef __attribute__((ext_vector_type(8))) short short8;   // 8 bf16 in 4 VGPRs
typedef __attribute__((ext_vector_type(4))) float floatx4;  // MFMA C/D

__device__ __forceinline__ short f2bf(float f) {
    __hip_bfloat16 h = __float2bfloat16(f);  // RNE
    short s;
    __builtin_memcpy(&s, &h, 2);
    return s;
}

__device__ __forceinline__ uint2 pack4bf(float a, float b, float cc, float d) {
    __hip_bfloat162 lo = __float22bfloat162_rn(float2{a, b});
    __hip_bfloat162 hi = __float22bfloat162_rn(float2{cc, d});
    uint2 r;
    __builtin_memcpy(&r.x, &lo, 4);
    __builtin_memcpy(&r.y, &hi, 4);
    return r;
}

// ---------------------------------------------------------------------------
// prep: build WqT[512][64], WoT[512][512] (bf16, transposed). 1024x256 threads.
// ---------------------------------------------------------------------------
__global__ void prep_kernel(const float* __restrict__ Wq, const float* __restrict__ Wo,
                            short* __restrict__ WqT, short* __restrict__ WoT) {
    int idx = blockIdx.x * 256 + threadIdx.x;             // 0 .. 262143
    if (idx < HD * DKK) {                                 // 32768
        int o = idx >> 6, i = idx & 63;                   // WqT[o][i] = Wq[i][o]
        WqT[idx] = f2bf(Wq[i * HD + o]);
    }
    {                                                     // 262144 exactly
        int o = idx >> 9, i = idx & 511;                  // WoT[o][i] = Wo[i][o]
        WoT[idx] = f2bf(Wo[i * DM + o]);
    }
}

// ---------------------------------------------------------------------------
// maskbits: bit=1 where mask==1.0 (those positions get -inf). 1 bit per entry.
// ---------------------------------------------------------------------------
__global__ void maskbits_kernel(const float* __restrict__ mask,
                                unsigned long long* __restrict__ bits) {
    size_t idx = (size_t)blockIdx.x * 256 + threadIdx.x;  // < 33554432
    float val = mask[idx];
    unsigned long long bal = __ballot(val == 1.0f);
    if ((threadIdx.x & 63) == 0) bits[idx >> 6] = bal;
}

// ---------------------------------------------------------------------------
// Generic C = alpha*(A * B^T + bias).  A:[M][K] row-major, Bt:[N][K] row-major.
// A_F32/B_F32: input is fp32, converted to bf16 during LDS staging.
// Block 256 thr = 4 waves in 2x2; tile 128x128; BK=64; 16x16x32 bf16 MFMA.
// ---------------------------------------------------------------------------
template <bool OUT_F32, bool BIAS_ROW, bool A_F32, bool B_F32>
__global__ __launch_bounds__(256, 2) void gemm_bt(
    const void* __restrict__ A_, int lda, long sA,
    const void* __restrict__ B_, int ldb, long sB,
    void* __restrict__ C, int ldc, long sC,
    const float* __restrict__ bias, int K, float alpha) {
    const int bz = blockIdx.z;
    const int m0 = blockIdx.y * 128, n0 = blockIdx.x * 128;
    __shared__ __align__(16) short As[128 * 80];
    __shared__ __align__(16) short Bs[128 * 80];
    const int tid = threadIdx.x, lane = tid & 63, w = tid >> 6;
    const int c = lane & 15, Q = lane >> 4;
    const int wm = w >> 1, wn = w & 1;
    floatx4 acc[4][4] = {};

    for (int k0 = 0; k0 < K; k0 += 64) {
#pragma unroll
        for (int it = 0; it < 4; ++it) {
            int chunk = it * 256 + tid;          // 1024 chunks of 8 shorts each side
            int row = chunk >> 3, c8 = chunk & 7;
            size_t aoff = (size_t)bz * sA + (size_t)(m0 + row) * lda + k0 + c8 * 8;
            size_t boff = (size_t)bz * sB + (size_t)(n0 + row) * ldb + k0 + c8 * 8;
            if (A_F32) {
                const float* Af = (const float*)A_ + aoff;
                float4 lo = *(const float4*)Af;
                float4 hi = *(const float4*)(Af + 4);
                uint2 p0 = pack4bf(lo.x, lo.y, lo.z, lo.w);
                uint2 p1 = pack4bf(hi.x, hi.y, hi.z, hi.w);
                *(uint4*)&As[row * 80 + c8 * 8] = uint4{p0.x, p0.y, p1.x, p1.y};
            } else {
                *(uint4*)&As[row * 80 + c8 * 8] = *(const uint4*)((const short*)A_ + aoff);
            }
            if (B_F32) {
                const float* Bf = (const float*)B_ + boff;
                float4 lo = *(const float4*)Bf;
                float4 hi = *(const float4*)(Bf + 4);
                uint2 p0 = pack4bf(lo.x, lo.y, lo.z, lo.w);
                uint2 p1 = pack4bf(hi.x, hi.y, hi.z, hi.w);
                *(uint4*)&Bs[row * 80 + c8 * 8] = uint4{p0.x, p0.y, p1.x, p1.y};
            } else {
                *(uint4*)&Bs[row * 80 + c8 * 8] = *(const uint4*)((const short*)B_ + boff);
            }
        }
        __syncthreads();
#pragma unroll
        for (int ks = 0; ks < 2; ++ks) {
            short8 af[4], bf[4];
#pragma unroll
            for (int mt = 0; mt < 4; ++mt)
                af[mt] = *(const short8*)&As[(wm * 64 + mt * 16 + c) * 80 + ks * 32 + 8 * Q];
#pragma unroll
            for (int nt = 0; nt < 4; ++nt)
                bf[nt] = *(const short8*)&Bs[(wn * 64 + nt * 16 + c) * 80 + ks * 32 + 8 * Q];
#pragma unroll
            for (int mt = 0; mt < 4; ++mt)
#pragma unroll
                for (int nt = 0; nt < 4; ++nt)
                    acc[mt][nt] = __builtin_amdgcn_mfma_f32_16x16x32_bf16(
                        af[mt], bf[nt], acc[mt][nt], 0, 0, 0);
        }
        __syncthreads();
    }
    // epilogue: row = m0+wm*64+mt*16+4Q+r, col = n0+wn*64+nt*16+c
#pragma unroll
    for (int mt = 0; mt < 4; ++mt)
#pragma unroll
        for (int nt = 0; nt < 4; ++nt) {
            int col = n0 + wn * 64 + nt * 16 + c;
            float bc = BIAS_ROW ? 0.f : bias[col];
#pragma unroll
            for (int r = 0; r < 4; ++r) {
                int row = m0 + wm * 64 + mt * 16 + 4 * Q + r;
                float val = (acc[mt][nt][r] + (BIAS_ROW ? bias[row] : bc)) * alpha;
                if (OUT_F32)
                    ((float*)C)[(size_t)bz * sC + (size_t)row * ldc + col] = val;
                else
                    ((short*)C)[(size_t)bz * sC + (size_t)row * ldc + col] = f2bf(val);
            }
        }
}

// ---------------------------------------------------------------------------
// Flash attention, S^T formulation: S^T = K*Q^T so each lane's scores belong to
// ONE q-row (col c). Block = 256 thr (4 waves), 64 q-rows/block, 16/wave.
// qh pre-scaled by log2(e)/8 so softmax runs in exp2 domain.
// K staged in LDS (shared by 4 waves); V-fragments loaded direct global->VGPR;
// P written to per-wave-private LDS (b64 packed), read back as A-frags (b128).
// ---------------------------------------------------------------------------
__global__ __launch_bounds__(256, 4) void fa_kernel(
    const short* __restrict__ qh, const short* __restrict__ kh,
    const short* __restrict__ vhT, const unsigned* __restrict__ mbits,
    short* __restrict__ y) {
    const int qt = blockIdx.x;         // 0..31
    const int bh = blockIdx.y;         // 0..63
    const int b = bh >> 3, h = bh & 7;
    const int tid = threadIdx.x, lane = tid & 63, w = tid >> 6;   // w 0..3
    const int c = lane & 15, Q = lane >> 4;

    __shared__ __align__(16) short smem[18944];  // Ks 10240 + 4*2176 P = 37,888 B
    short* Ks = smem;                      // 128 rows, stride 80
    short* Ps = smem + 10240 + w * 2176;   // per-wave 16 rows, stride 136

    // Q as B-fragment (n = q-col = c), loop-invariant
    const int qrow = qt * 64 + w * 16 + c;
    const short* qbase = qh + ((size_t)(b * SS + qrow)) * HD + h * DKK;
    short8 qf0 = *(const short8*)(qbase + 8 * Q);
    short8 qf1 = *(const short8*)(qbase + 32 + 8 * Q);

    const unsigned* mrow = mbits + (size_t)(b * SS + qrow) * 64;
    const short* vbase = vhT + ((size_t)(b * HD + h * DKK)) * SS;

    floatx4 o_acc[4] = {};
    float m_i = -INFINITY, l_i = 0.f;

    for (int kt = 0; kt < 16; ++kt) {
        // ---- stage K tile (128x64) ----
#pragma unroll
        for (int it = 0; it < 4; ++it) {
            int chunk = it * 256 + tid;      // 1024 chunks of 16B
            int row = chunk >> 3, c8 = chunk & 7;
            *(uint4*)&Ks[row * 80 + c8 * 8] =
                *(const uint4*)(kh + ((size_t)(b * SS + kt * 128 + row)) * HD + h * DKK + c8 * 8);
        }
        uint4 mr = *(const uint4*)(mrow + kt * 4);   // this q-row's 128 mask bits
        __syncthreads();

        // ---- S^T = K Q^T : s_acc[jt][r] = S^T[16jt+4Q+r][c] ----
        floatx4 s_acc[8];
#pragma unroll
        for (int jt = 0; jt < 8; ++jt) {
            short8 k0 = *(const short8*)&Ks[(jt * 16 + c) * 80 + 8 * Q];
            short8 k1 = *(const short8*)&Ks[(jt * 16 + c) * 80 + 32 + 8 * Q];
            floatx4 s = {};
            s = __builtin_amdgcn_mfma_f32_16x16x32_bf16(k0, qf0, s, 0, 0, 0);
            s = __builtin_amdgcn_mfma_f32_16x16x32_bf16(k1, qf1, s, 0, 0, 0);
            s_acc[jt] = s;
        }

        // ---- mask + per-lane (single-row) online softmax, exp2 domain ----
        unsigned mw[4] = {mr.x, mr.y, mr.z, mr.w};
        float mxr[4] = {-INFINITY, -INFINITY, -INFINITY, -INFINITY};
#pragma unroll
        for (int jt = 0; jt < 8; ++jt) {
            unsigned nib = (mw[jt >> 1] >> (((jt & 1) << 4) + 4 * Q)) & 0xFu;
#pragma unroll
            for (int r = 0; r < 4; ++r) {
                float t = (nib & (1u << r)) ? -INFINITY : s_acc[jt][r];
                s_acc[jt][r] = t;
                mxr[r] = fmaxf(mxr[r], t);
            }
        }
        float mx = fmaxf(fmaxf(mxr[0], mxr[1]), fmaxf(mxr[2], mxr[3]));
        mx = fmaxf(mx, __shfl_xor(mx, 16));
        mx = fmaxf(mx, __shfl_xor(mx, 32));
        float mnew = fmaxf(m_i, mx);
        float msafe = (mnew == -INFINITY) ? 0.f : mnew;
        float al = exp2f(m_i - msafe);
        float ps = 0.f;
#pragma unroll
        for (int jt = 0; jt < 8; ++jt) {
            float p0 = exp2f(s_acc[jt][0] - msafe);
            float p1 = exp2f(s_acc[jt][1] - msafe);
            float p2 = exp2f(s_acc[jt][2] - msafe);
            float p3 = exp2f(s_acc[jt][3] - msafe);
            ps += (p0 + p1) + (p2 + p3);
            // P row-major: row c, k = 16jt+4Q+{0..3} -> one 8B write
            *(uint2*)&Ps[c * 136 + jt * 16 + 4 * Q] = pack4bf(p0, p1, p2, p3);
        }
        ps += __shfl_xor(ps, 16);
        ps += __shfl_xor(ps, 32);
        l_i = l_i * al + ps;
        m_i = mnew;

        // ---- rescale O (needs al of C-layout row 4Q+r) ----
        float al_r[4];
#pragma unroll
        for (int r = 0; r < 4; ++r) al_r[r] = __shfl(al, 4 * Q + r);
#pragma unroll
        for (int nt = 0; nt < 4; ++nt)
#pragma unroll
            for (int r = 0; r < 4; ++r) o_acc[nt][r] *= al_r[r];

        asm volatile("s_waitcnt lgkmcnt(0)" ::: "memory");  // P writes visible to own wave
        short8 pa[4];
#pragma unroll
        for (int ks = 0; ks < 4; ++ks)
            pa[ks] = *(const short8*)&Ps[c * 136 + ks * 32 + 8 * Q];

        // ---- O += P V  (V^T B-frags direct from global; L1-resident tile) ----
#pragma unroll
        for (int nt = 0; nt < 4; ++nt) {
            short8 vf[4];
#pragma unroll
            for (int ks = 0; ks < 4; ++ks)
                vf[ks] = *(const short8*)(vbase + (size_t)(nt * 16 + c) * SS + kt * 128 + ks * 32 + 8 * Q);
#pragma unroll
            for (int ks = 0; ks < 4; ++ks)
                o_acc[nt] = __builtin_amdgcn_mfma_f32_16x16x32_bf16(pa[ks], vf[ks], o_acc[nt], 0, 0, 0);
        }
        __syncthreads();   // Ks dead; safe to restage next iter
    }

    // ---- epilogue: O/l -> y bf16 ----
    float l4[4];
#pragma unroll
    for (int r = 0; r < 4; ++r) l4[r] = __shfl(l_i, 4 * Q + r);
#pragma unroll
    for (int r = 0; r < 4; ++r) {
        float inv = 1.0f / l4[r];
        int row = qt * 64 + w * 16 + 4 * Q + r;
#pragma unroll
        for (int nt = 0; nt < 4; ++nt)
            y[((size_t)(b * SS + row)) * HD + h * DKK + nt * 16 + c] = f2bf(o_acc[nt][r] * inv);
    }
}

// ---------------------------------------------------------------------------
extern "C" void kernel_launch(void* const* d_in, const int* in_sizes, int n_in,
                              void* d_out, int out_size, void* d_ws, size_t ws_size,
                              hipStream_t stream) {
    const float* q    = (const float*)d_in[0];
    const float* k    = (const float*)d_in[1];
    const float* v    = (const float*)d_in[2];
    const float* mask = (const float*)d_in[3];
    const float* Wq   = (const float*)d_in[4];
    const float* bq   = (const float*)d_in[5];
    const float* Wo   = (const float*)d_in[6];
    const float* bo   = (const float*)d_in[7];

    char* ws = (char*)d_ws;
    const size_t MB = 1ull << 20;
    short* WqT = (short*)(ws + 0 * MB);    // 64 KB
    short* WoT = (short*)(ws + 1 * MB);    // 512 KB
    short* qh  = (short*)(ws + 8 * MB);    // 16 MB  [b][s][hd]  (pre-scaled by log2e/8)
    short* kh  = (short*)(ws + 24 * MB);   // 16 MB  [b][s][hd]
    short* vhT = (short*)(ws + 40 * MB);   // 16 MB  [b][hd][s]
    unsigned long long* bits = (unsigned long long*)(ws + 56 * MB);  // 4 MB
    short* yb  = (short*)(ws + 60 * MB);   // 16 MB  [b][s][hd]
    float* out = (float*)d_out;

    const float ALPHA_Q = 0.18033688011f;  // log2(e)/8: folds 1/sqrt(64) and exp->exp2

    prep_kernel<<<1024, 256, 0, stream>>>(Wq, Wo, WqT, WoT);
    maskbits_kernel<<<131072, 256, 0, stream>>>(mask, bits);

    // qh = (q @ Wq + bq) * alpha ; kh = k @ Wq + bq   (M=16384, N=512, K=64)
    gemm_bt<false, false, true, false><<<dim3(4, 128, 1), 256, 0, stream>>>(
        q, 64, 0, WqT, 64, 0, (void*)qh, 512, 0, bq, 64, ALPHA_Q);
    gemm_bt<false, false, true, false><<<dim3(4, 128, 1), 256, 0, stream>>>(
        k, 64, 0, WqT, 64, 0, (void*)kh, 512, 0, bq, 64, 1.0f);
    // vhT[b][hd][s] = WqT @ v_b^T + bq (row bias): M=512, N=2048, K=64, batched
    gemm_bt<false, true, false, true><<<dim3(16, 4, BB), 256, 0, stream>>>(
        WqT, 64, 0, v, 64, (long)SS * DKK, (void*)vhT, SS, (long)HD * SS, bq, 64, 1.0f);

    fa_kernel<<<dim3(32, 64, 1), 256, 0, stream>>>(qh, kh, vhT, (const unsigned*)bits, yb);

    // out = y @ Wo + bo  (M=16384, N=512, K=512), fp32 out
    gemm_bt<true, false, false, false><<<dim3(4, 128, 1), 256, 0, stream>>>(
        yb, 512, 0, WoT, 512, 0, (void*)out, 512, 0, bo, 512, 1.0f);
}